// Round 5
// baseline (915.403 us; speedup 1.0000x reference)
//
#include <hip/hip_runtime.h>

// LSTM RNN_20263655702953 — MI355X (gfx950), round 9.
//
// Reference quirk: hs[:, -1, :] selects BATCH index 511 => single sequential
// LSTM chain (1024 steps, H=64), then (1024,64)@(64,2) projection.
//
// R9: single-wave recurrence, REGISTER-BUDGET FIXED. R7/R8 both spilled
// (VGPR_Count 144-148, ~780 VALU/step vs ~400 source = AGPR/scratch copy
// overhead). R8's real demand was ~253 regs — at the 256 cap. R9 cuts to
// ~223 with margin:
//   - resident weights: gate 0 only (w0[64] = 64 VGPRs)
//   - gates 1,2,3 streamed from LDS (transposed [k4][lane] float4 layout,
//     conflict-free contiguous b128), 16-k batches (12 x ds_read_b128),
//     double-buffered, prefetched TWO batches (~320cy) ahead of use
//     (R8's 1-batch distance was marginal: 144cy pipe vs 160cy cover).
//   - h broadcast: proven zero-latency readlane (R4 pattern, hsA/hsB,
//     sched_barrier(0) fences).
// Zero barriers / zero cross-wave ops in the loop. LDS pipe 48x12=576cy
// fully overlapped under ~830cy VALU issue.
// Model: ~920cy/step => ~395us. Falsifier: VGPR_Count ~144 again => the
// allocator is structurally defeated => revert to 4-wave R4 structure.

#define T_LEN 1024
#define BATCH 512
#define HID   64

__device__ __forceinline__ float fast_rcp(float x) {
    return __builtin_amdgcn_rcpf(x);  // v_rcp_f32, ~1e-7 rel err
}
__device__ __forceinline__ float fast_tanh(float x) {
    // 1 - 2/(e^{2x}+1); saturates correctly for |x| large
    return 1.0f - 2.0f * fast_rcp(__expf(2.0f * x) + 1.0f);
}

#define RL16(DST, OFF)                                                      \
    _Pragma("unroll")                                                       \
    for (int k = 0; k < 16; ++k) DST[k] = __builtin_amdgcn_readlane(hb, (OFF) + k);

// Prefetch one 16-k batch (k4 columns K4..K4+3) for gates 1,2,3 into P1/P2/P3.
#define PREF(P1, P2, P3, K4)                                                \
    _Pragma("unroll")                                                       \
    for (int j = 0; j < 4; ++j) {                                           \
        P1[j] = Tw[0][((K4) + j) * HID + lane];                             \
        P2[j] = Tw[1][((K4) + j) * HID + lane];                             \
        P3[j] = Tw[2][((K4) + j) * HID + lane];                             \
    }

// One 16-k batch: 64 FMAs. Gate 0 from resident w0; gates 1,2,3 from
// streamed float4 regs P1/P2/P3.
#define FMAB(BASE, HS, P1, P2, P3)                                          \
    _Pragma("unroll")                                                       \
    for (int j = 0; j < 4; ++j) {                                           \
        const float h0 = __int_as_float(HS[4*j+0]);                         \
        const float h1 = __int_as_float(HS[4*j+1]);                         \
        const float h2 = __int_as_float(HS[4*j+2]);                         \
        const float h3 = __int_as_float(HS[4*j+3]);                         \
        ai = fmaf(w0[(BASE)+4*j+0], h0, ai);                                \
        af = fmaf(P1[j].x, h0, af);                                         \
        ag = fmaf(P2[j].x, h0, ag);                                         \
        ao = fmaf(P3[j].x, h0, ao);                                         \
        ai = fmaf(w0[(BASE)+4*j+1], h1, ai);                                \
        af = fmaf(P1[j].y, h1, af);                                         \
        ag = fmaf(P2[j].y, h1, ag);                                         \
        ao = fmaf(P3[j].y, h1, ao);                                         \
        ai = fmaf(w0[(BASE)+4*j+2], h2, ai);                                \
        af = fmaf(P1[j].z, h2, af);                                         \
        ag = fmaf(P2[j].z, h2, ag);                                         \
        ao = fmaf(P3[j].z, h2, ao);                                         \
        ai = fmaf(w0[(BASE)+4*j+3], h3, ai);                                \
        af = fmaf(P1[j].w, h3, af);                                         \
        ag = fmaf(P2[j].w, h3, ag);                                         \
        ao = fmaf(P3[j].w, h3, ao);                                         \
    }

__global__ __launch_bounds__(256, 1)
void lstm_seq_kernel(const float* __restrict__ x,
                     const float* __restrict__ W_ih,
                     const float* __restrict__ W_hh,
                     const float* __restrict__ b_ih,
                     const float* __restrict__ b_hh,
                     const float* __restrict__ W_fc,
                     const float* __restrict__ b_fc,
                     float* __restrict__ out,
                     float* __restrict__ hist)   // d_ws: 1024*64 floats
{
    __shared__ float  xs[2 * T_LEN];     // 8 KB: x[:,511,:]
    __shared__ float4 Tw[3][16 * HID];   // 48 KB: gates 1,2,3 weights, [k4][lane]

    const int tid  = threadIdx.x;
    const int lane = tid & 63;
    const int wave = tid >> 6;

    // ---- stage x[:,511,:] into LDS (all 4 waves, one-time)
    for (int j = 0; j < 4; ++j) {
        int t = tid + j * 256;              // 0..1023
        const float2 v = *(const float2*)(x + (size_t)(t * BATCH + (BATCH - 1)) * 2);
        xs[2 * t]     = v.x;
        xs[2 * t + 1] = v.y;
    }
    // ---- stage gates 1,2,3 weights transposed: Tw[g-1][k4*64+l] = W_hh[g*64+l][4k4..]
    {
        const float4* W4 = (const float4*)W_hh;
        for (int idx = tid; idx < 3072; idx += 256) {
            const int g   = idx >> 10;          // 0..2  (gates 1..3)
            const int rem = idx & 1023;
            const int l   = rem >> 4;           // 0..63
            const int k4  = rem & 15;           // 0..15
            Tw[g][k4 * HID + l] = W4[((g + 1) * HID + l) * 16 + k4];
        }
    }
    __syncthreads();                        // xs + Tw visible to wave 0

    if (wave == 0) {
        // ---- gate 0 weights resident in VGPRs (64 regs)
        float w0[HID];
        {
            const float4* r0 = (const float4*)(W_hh + lane * HID);
            #pragma unroll
            for (int k = 0; k < 16; ++k) {
                float4 a = r0[k];
                w0[4*k+0] = a.x; w0[4*k+1] = a.y; w0[4*k+2] = a.z; w0[4*k+3] = a.w;
            }
        }
        float wi0[4], wi1[4], bs[4];
        #pragma unroll
        for (int g = 0; g < 4; ++g) {
            const int row = g * HID + lane;
            wi0[g] = W_ih[row * 2 + 0];
            wi1[g] = W_ih[row * 2 + 1];
            bs[g]  = b_ih[row] + b_hh[row];
        }

        // ---- double-buffered streamed weights for gates 1,2,3 (96 regs)
        float4 A1[4], A2[4], A3[4], B1[4], B2[4], B3[4];
        PREF(A1, A2, A3, 0);                // A <- k=0..15
        PREF(B1, B2, B3, 4);                // B <- k=16..31

        float hval = 0.0f;   // lane l holds h[l]
        float cval = 0.0f;   // lane l holds c[l]

        for (int t = 0; t < T_LEN; ++t) {
            const float2 xv = *(const float2*)(xs + 2 * t);   // uniform bcast
            const int hb = __float_as_int(hval);

            float ai = bs[0], af = bs[1], ag = bs[2], ao = bs[3];
            int hsA[16], hsB[16];

            RL16(hsA, 0);                               // h[0..15]
            __builtin_amdgcn_sched_barrier(0);

            FMAB(0, hsA, A1, A2, A3);                   // k=0..15  (A)
            PREF(A1, A2, A3, 8);                        // A <- k=32..47 (used 2 batches later)
            RL16(hsB, 16);                              // h[16..31]
            __builtin_amdgcn_sched_barrier(0);

            FMAB(16, hsB, B1, B2, B3);                  // k=16..31 (B)
            PREF(B1, B2, B3, 12);                       // B <- k=48..63
            RL16(hsA, 32);                              // h[32..47]
            __builtin_amdgcn_sched_barrier(0);

            FMAB(32, hsA, A1, A2, A3);                  // k=32..47 (A)
            PREF(A1, A2, A3, 0);                        // A <- next step k=0..15
            RL16(hsB, 48);                              // h[48..63]
            __builtin_amdgcn_sched_barrier(0);

            FMAB(48, hsB, B1, B2, B3);                  // k=48..63 (B)
            PREF(B1, B2, B3, 4);                        // B <- next step k=16..31

            // x contribution last (its LDS read long since drained)
            ai = fmaf(wi1[0], xv.y, fmaf(wi0[0], xv.x, ai));
            af = fmaf(wi1[1], xv.y, fmaf(wi0[1], xv.x, af));
            ag = fmaf(wi1[2], xv.y, fmaf(wi0[2], xv.x, ag));
            ao = fmaf(wi1[3], xv.y, fmaf(wi0[3], xv.x, ao));

            // ---- activations (independent chains, ILP)
            const float gi = fast_rcp(1.0f + __expf(-ai));
            const float gf = fast_rcp(1.0f + __expf(-af));
            const float go = fast_rcp(1.0f + __expf(-ao));
            const float gg = fmaf(2.0f, fast_rcp(1.0f + __expf(-2.0f * ag)), -1.0f);

            // ---- lane-local update (no exchange, no barrier)
            cval = fmaf(gf, cval, gi * gg);
            hval = go * fast_tanh(cval);

            // h history: coalesced 256B store; never waited on in-loop
            hist[t * HID + lane] = hval;
        }
    }

    __syncthreads();  // wave0's hist stores drained (vmcnt 0) & visible

    // ---- projection: out[t,o] = b_fc[o] + dot(W_fc[o,:], hist[t,:])
    #pragma unroll
    for (int j = 0; j < 8; ++j) {
        const int idx = tid + j * 256;      // 0..2047, coalesced stores
        const int t   = idx >> 1;
        const int o   = idx & 1;
        const float4* hv4 = (const float4*)(hist + t * HID);
        const float4* wv  = (const float4*)(W_fc + o * HID);
        float p0 = 0.f, p1 = 0.f, p2 = 0.f, p3 = 0.f;
        #pragma unroll
        for (int k = 0; k < HID / 4; ++k) {
            float4 h4 = hv4[k], w4 = wv[k];
            p0 = fmaf(h4.x, w4.x, p0);
            p1 = fmaf(h4.y, w4.y, p1);
            p2 = fmaf(h4.z, w4.z, p2);
            p3 = fmaf(h4.w, w4.w, p3);
        }
        out[idx] = b_fc[o] + ((p0 + p1) + (p2 + p3));
    }
}

extern "C" void kernel_launch(void* const* d_in, const int* in_sizes, int n_in,
                              void* d_out, int out_size, void* d_ws, size_t ws_size,
                              hipStream_t stream) {
    const float* x    = (const float*)d_in[0];
    const float* W_ih = (const float*)d_in[1];
    const float* W_hh = (const float*)d_in[2];
    const float* b_ih = (const float*)d_in[3];
    const float* b_hh = (const float*)d_in[4];
    const float* W_fc = (const float*)d_in[5];
    const float* b_fc = (const float*)d_in[6];
    float* out  = (float*)d_out;
    float* hist = (float*)d_ws;   // needs 1024*64*4 = 256 KB

    lstm_seq_kernel<<<dim3(1), dim3(256), 0, stream>>>(
        x, W_ih, W_hh, b_ih, b_hh, W_fc, b_fc, out, hist);
}

// Round 6
// 596.295 us; speedup vs baseline: 1.5352x; 1.5352x over previous
//
#include <hip/hip_runtime.h>

// LSTM RNN_20263655702953 — MI355X (gfx950), round 10.
//
// Reference quirk: hs[:, -1, :] selects BATCH index 511 => single sequential
// LSTM chain (1024 steps, H=64), then (1024,64)@(64,2) projection.
//
// R10: K-SPLIT 4-wave structure. Single-wave (R7-R9) is allocator-defeated:
// VGPR_Count pinned at ~144 with ~350 spill-copy VALU/step across three
// register budgets. R4 (gate-per-wave, 76 VGPR, 425us) allocates cleanly but
// spends half its issue on a 64-wide readlane broadcast + carries the gate
// exchange. R10 splits the DOT (K) across waves instead of the gates:
//   - wave q owns h[16q..16q+16): only 16 readlanes/wave (h replicated).
//   - lane l computes partials for all 4 rows {g*64+l} over its slice:
//     64 FMA/wave (w[4][16] = 64 VGPRs -> total ~125, safe regime).
//   - exchange = 4-way partial reduction: 4 conflict-free b32 writes,
//     lgkm-only barrier, 16 conflict-free b32 reads (pairable ds_read2),
//     double-buffered part[2][q][g][unit].
//   - all 4 gate activations + c,h update computed per-lane in EVERY wave
//     (keeps h,c replicated => next step's readlane is in-wave).
//   - x+bias seeded only in wave 0's partial via masked constants (no branch).
//   - hist stored directly by wave 0; lgkm-only barrier never drains vmcnt;
//     final __syncthreads() (full drain) makes hist visible for projection.
// Model ~550cy/step => ~240us ideal, predict 280-360us measured.

#define T_LEN 1024
#define BATCH 512
#define HID   64

__device__ __forceinline__ float fast_rcp(float x) {
    return __builtin_amdgcn_rcpf(x);  // v_rcp_f32, ~1e-7 rel err
}
__device__ __forceinline__ float fast_tanh(float x) {
    // 1 - 2/(e^{2x}+1); saturates correctly for |x| large
    return 1.0f - 2.0f * fast_rcp(__expf(2.0f * x) + 1.0f);
}
__device__ __forceinline__ void fast_barrier() {
    // LDS-only drain + barrier; deliberately no vmcnt (hist stores in flight)
    asm volatile("s_waitcnt lgkmcnt(0)\n\ts_barrier" ::: "memory");
}

__global__ __launch_bounds__(256, 1)
void lstm_seq_kernel(const float* __restrict__ x,
                     const float* __restrict__ W_ih,
                     const float* __restrict__ W_hh,
                     const float* __restrict__ b_ih,
                     const float* __restrict__ b_hh,
                     const float* __restrict__ W_fc,
                     const float* __restrict__ b_fc,
                     float* __restrict__ out,
                     float* __restrict__ hist)   // d_ws: 1024*64 floats
{
    __shared__ float xs[2 * T_LEN];          // 8 KB: x[:,511,:]
    __shared__ float part[2][4][4][HID];     // 8 KB: [buf][wave q][gate][unit]

    const int tid  = threadIdx.x;
    const int lane = tid & 63;
    const int q    = tid >> 6;               // wave id = K-slice owner

    // ---- stage x[:,511,:] into LDS (one-time)
    for (int j = 0; j < 4; ++j) {
        int t = tid + j * 256;               // 0..1023
        const float2 v = *(const float2*)(x + (size_t)(t * BATCH + (BATCH - 1)) * 2);
        xs[2 * t]     = v.x;
        xs[2 * t + 1] = v.y;
    }

    // ---- weights: lane l, wave q holds W_hh[g*64+l][16q+j], g=0..3, j=0..15
    float w[4][16];
    #pragma unroll
    for (int g = 0; g < 4; ++g) {
        const float4* wr = (const float4*)(W_hh + (size_t)(g * HID + lane) * HID + 16 * q);
        #pragma unroll
        for (int k = 0; k < 4; ++k) {
            float4 v = wr[k];
            w[g][4*k+0] = v.x; w[g][4*k+1] = v.y;
            w[g][4*k+2] = v.z; w[g][4*k+3] = v.w;
        }
    }
    // x+bias contribution folded into wave 0's partial only (masked, branchless)
    float wi0s[4], wi1s[4], bss[4];
    #pragma unroll
    for (int g = 0; g < 4; ++g) {
        const int   row = g * HID + lane;
        const float m   = (q == 0) ? 1.0f : 0.0f;
        wi0s[g] = m * W_ih[row * 2 + 0];
        wi1s[g] = m * W_ih[row * 2 + 1];
        bss[g]  = m * (b_ih[row] + b_hh[row]);
    }
    __syncthreads();                         // xs visible everywhere

    float hval = 0.0f;   // lane l holds h[l]  (replicated in every wave)
    float cval = 0.0f;   // lane l holds c[l]

    for (int t = 0; t < T_LEN; ++t) {
        const float2 xv = *(const float2*)(xs + 2 * t);   // uniform bcast
        const int hb = __float_as_int(hval);

        // ---- h broadcast: ONLY this wave's 16-slice (zero-latency readlane)
        int hs[16];
        #pragma unroll
        for (int j = 0; j < 16; ++j) hs[j] = __builtin_amdgcn_readlane(hb, 16 * q + j);
        __builtin_amdgcn_sched_barrier(0);

        // seed (wave 0 carries x+bias; others start at 0) — 8 FMAs, no branch
        float a0 = fmaf(wi1s[0], xv.y, fmaf(wi0s[0], xv.x, bss[0]));
        float a1 = fmaf(wi1s[1], xv.y, fmaf(wi0s[1], xv.x, bss[1]));
        float a2 = fmaf(wi1s[2], xv.y, fmaf(wi0s[2], xv.x, bss[2]));
        float a3 = fmaf(wi1s[3], xv.y, fmaf(wi0s[3], xv.x, bss[3]));

        // ---- 64 FMAs: 4 rows x 16-wide K-slice (4 independent chains)
        #pragma unroll
        for (int j = 0; j < 16; ++j) {
            const float hj = __int_as_float(hs[j]);
            a0 = fmaf(w[0][j], hj, a0);
            a1 = fmaf(w[1][j], hj, a1);
            a2 = fmaf(w[2][j], hj, a2);
            a3 = fmaf(w[3][j], hj, a3);
        }

        // ---- publish partials (4 conflict-free b32 writes)
        const int buf = t & 1;
        part[buf][q][0][lane] = a0;
        part[buf][q][1][lane] = a1;
        part[buf][q][2][lane] = a2;
        part[buf][q][3][lane] = a3;
        fast_barrier();                      // the only per-step barrier (lgkm-only)

        // ---- reduce partials (16 conflict-free b32 reads, read2-pairable)
        float p[4][4];
        #pragma unroll
        for (int qq = 0; qq < 4; ++qq)
            #pragma unroll
            for (int g = 0; g < 4; ++g) p[qq][g] = part[buf][qq][g][lane];
        const float s0 = (p[0][0] + p[1][0]) + (p[2][0] + p[3][0]);
        const float s1 = (p[0][1] + p[1][1]) + (p[2][1] + p[3][1]);
        const float s2 = (p[0][2] + p[1][2]) + (p[2][2] + p[3][2]);
        const float s3 = (p[0][3] + p[1][3]) + (p[2][3] + p[3][3]);

        // ---- activations (4 independent chains) + lane-local update
        const float gi = fast_rcp(1.0f + __expf(-s0));
        const float gf = fast_rcp(1.0f + __expf(-s1));
        const float gg = fmaf(2.0f, fast_rcp(1.0f + __expf(-2.0f * s2)), -1.0f);
        const float go = fast_rcp(1.0f + __expf(-s3));
        cval = fmaf(gf, cval, gi * gg);
        hval = go * fast_tanh(cval);

        // h history: wave 0 stores directly (coalesced 256B; never drained in-loop)
        if (q == 0) hist[t * HID + lane] = hval;
    }

    __syncthreads();  // full drain: wave0's hist stores visible to all

    // ---- projection: out[t,o] = b_fc[o] + dot(W_fc[o,:], hist[t,:])
    #pragma unroll
    for (int j = 0; j < 8; ++j) {
        const int idx = tid + j * 256;      // 0..2047, coalesced stores
        const int t   = idx >> 1;
        const int o   = idx & 1;
        const float4* hv4 = (const float4*)(hist + t * HID);
        const float4* wv  = (const float4*)(W_fc + o * HID);
        float p0 = 0.f, p1 = 0.f, p2 = 0.f, p3 = 0.f;
        #pragma unroll
        for (int k = 0; k < HID / 4; ++k) {
            float4 h4 = hv4[k], w4 = wv[k];
            p0 = fmaf(h4.x, w4.x, p0);
            p1 = fmaf(h4.y, w4.y, p1);
            p2 = fmaf(h4.z, w4.z, p2);
            p3 = fmaf(h4.w, w4.w, p3);
        }
        out[idx] = b_fc[o] + ((p0 + p1) + (p2 + p3));
    }
}

extern "C" void kernel_launch(void* const* d_in, const int* in_sizes, int n_in,
                              void* d_out, int out_size, void* d_ws, size_t ws_size,
                              hipStream_t stream) {
    const float* x    = (const float*)d_in[0];
    const float* W_ih = (const float*)d_in[1];
    const float* W_hh = (const float*)d_in[2];
    const float* b_ih = (const float*)d_in[3];
    const float* b_hh = (const float*)d_in[4];
    const float* W_fc = (const float*)d_in[5];
    const float* b_fc = (const float*)d_in[6];
    float* out  = (float*)d_out;
    float* hist = (float*)d_ws;   // needs 1024*64*4 = 256 KB

    lstm_seq_kernel<<<dim3(1), dim3(256), 0, stream>>>(
        x, W_ih, W_hh, b_ih, b_hh, W_fc, b_fc, out, hist);
}

// Round 7
// 497.871 us; speedup vs baseline: 1.8386x; 1.1977x over previous
//
#include <hip/hip_runtime.h>

// LSTM RNN_20263655702953 — MI355X (gfx950), round 11.
//
// Reference quirk: hs[:, -1, :] selects BATCH index 511 => single sequential
// LSTM chain (1024 steps, H=64), then (1024,64)@(64,2) projection.
// One workgroup, 4 waves (1/SIMD); wave g owns gate g, lane l owns unit l.
//
// R11 = R4 (best, 425us) + isolated micro-shavings. Session evidence:
//  - R5/R6: any LDS hop on the h path loses to readlane (latency at head).
//  - R7-R9: single-wave needs >256 live floats; VALU only addresses v0-v255
//    => AGPR copy per use (~256 instr/step). Hardware dead end.
//  - R10: readlane with runtime lane index (16*q+j) => waterfall, 2.2x VALU.
//  - Clock calibration: at ~1.65GHz effective, R4 is self-consistent:
//    ~320cy issue (=source instr) + ~340cy barrier/LDS-latency/serial.
// R11 changes (all small, additive, structure-preserving):
//  1. lgkm-only barrier (no vmcnt drain: wave0's hist stores fly free).
//  2. hring dropped: direct coalesced 256B hist store per step by wave0.
//  3. Activations: premultiplied log2(e) constants + raw v_exp_f32 (exp2),
//     saving the internal x*1.4427 mul of __expf. 2 exps/wave/step.
//  4. Gate reads ordered i,f,g then o (o needed last), read2-pairable.

#define T_LEN 1024
#define BATCH 512
#define HID   64

__device__ __forceinline__ float fast_rcp(float x) {
    return __builtin_amdgcn_rcpf(x);  // v_rcp_f32, ~1e-7 rel err
}
__device__ __forceinline__ float fast_exp2(float x) {
    float r;
    asm("v_exp_f32 %0, %1" : "=v"(r) : "v"(x));   // 2^x, transcendental pipe
    return r;
}
__device__ __forceinline__ void fast_barrier() {
    // LDS-only drain + barrier; deliberately no vmcnt (hist stores in flight)
    asm volatile("s_waitcnt lgkmcnt(0)\n\ts_barrier" ::: "memory");
}

#define LOG2E 1.4426950408889634f

__global__ __launch_bounds__(256, 1)
void lstm_seq_kernel(const float* __restrict__ x,
                     const float* __restrict__ W_ih,
                     const float* __restrict__ W_hh,
                     const float* __restrict__ b_ih,
                     const float* __restrict__ b_hh,
                     const float* __restrict__ W_fc,
                     const float* __restrict__ b_fc,
                     float* __restrict__ out,
                     float* __restrict__ hist)   // d_ws: 1024*64 floats
{
    __shared__ float xs[2 * T_LEN];         // 8 KB: x[:,511,:]
    __shared__ float gbuf[2][4][HID];       // 2 KB: double-buffered gates [buf][gate][unit]

    const int tid  = threadIdx.x;
    const int lane = tid & 63;
    const int gate = tid >> 6;              // 0..3 = i,f,g,o ; == wave id
    const int row  = tid;                   // gate row in [0,256)

    // ---- stage x[:,511,:] into LDS (one-time)
    for (int j = 0; j < 4; ++j) {
        int t = tid + j * 256;              // 0..1023
        const float2 v = *(const float2*)(x + (size_t)(t * BATCH + (BATCH - 1)) * 2);
        xs[2 * t]     = v.x;
        xs[2 * t + 1] = v.y;
    }

    // ---- preload this lane's W_hh row (natural order) into VGPRs
    float w[HID];
    {
        const float4* wr = (const float4*)(W_hh + row * HID);
        #pragma unroll
        for (int k = 0; k < HID / 4; ++k) {
            float4 v = wr[k];
            w[4*k+0] = v.x; w[4*k+1] = v.y; w[4*k+2] = v.z; w[4*k+3] = v.w;
        }
    }
    const float bsum = b_ih[row] + b_hh[row];
    const float wi0  = W_ih[row * 2 + 0];
    const float wi1  = W_ih[row * 2 + 1];

    // unified activation constants, log2e premultiplied:
    // sigmoid: 1*rcp(1+2^(-log2e*x))+0 ; tanh: 2*rcp(1+2^(-2*log2e*x))-1
    const float actA  = (gate == 2) ? 2.0f : 1.0f;
    const float actB2 = (gate == 2) ? (-2.0f * LOG2E) : (-LOG2E);
    const float actC  = (gate == 2) ? -1.0f : 0.0f;

    float hval = 0.0f;   // lane l holds h[l]  (replicated in every wave)
    float cval = 0.0f;   // lane l holds c[l]

    __syncthreads();

    for (int t = 0; t < T_LEN; ++t) {
        // x-part load issued early (independent), consumed after FMA stream
        const float2 xv = *(const float2*)(xs + 2 * t);   // uniform bcast
        const int hb = __float_as_int(hval);

        float a0 = bsum, a1 = 0.0f, a2 = 0.0f, a3 = 0.0f;
        int hsA[16], hsB[16];

        // ---- RL batch 0
        #pragma unroll
        for (int k = 0; k < 16; ++k) hsA[k] = __builtin_amdgcn_readlane(hb, k);
        __builtin_amdgcn_sched_barrier(0);
        // ---- FMA batch 0 + RL batch 1
        #pragma unroll
        for (int k = 0; k < 16; k += 4) {
            a0 = fmaf(w[k+0], __int_as_float(hsA[k+0]), a0);
            a1 = fmaf(w[k+1], __int_as_float(hsA[k+1]), a1);
            a2 = fmaf(w[k+2], __int_as_float(hsA[k+2]), a2);
            a3 = fmaf(w[k+3], __int_as_float(hsA[k+3]), a3);
        }
        #pragma unroll
        for (int k = 0; k < 16; ++k) hsB[k] = __builtin_amdgcn_readlane(hb, 16 + k);
        __builtin_amdgcn_sched_barrier(0);
        // ---- FMA batch 1 + RL batch 2
        #pragma unroll
        for (int k = 0; k < 16; k += 4) {
            a0 = fmaf(w[16+k+0], __int_as_float(hsB[k+0]), a0);
            a1 = fmaf(w[16+k+1], __int_as_float(hsB[k+1]), a1);
            a2 = fmaf(w[16+k+2], __int_as_float(hsB[k+2]), a2);
            a3 = fmaf(w[16+k+3], __int_as_float(hsB[k+3]), a3);
        }
        #pragma unroll
        for (int k = 0; k < 16; ++k) hsA[k] = __builtin_amdgcn_readlane(hb, 32 + k);
        __builtin_amdgcn_sched_barrier(0);
        // ---- FMA batch 2 + RL batch 3
        #pragma unroll
        for (int k = 0; k < 16; k += 4) {
            a0 = fmaf(w[32+k+0], __int_as_float(hsA[k+0]), a0);
            a1 = fmaf(w[32+k+1], __int_as_float(hsA[k+1]), a1);
            a2 = fmaf(w[32+k+2], __int_as_float(hsA[k+2]), a2);
            a3 = fmaf(w[32+k+3], __int_as_float(hsA[k+3]), a3);
        }
        #pragma unroll
        for (int k = 0; k < 16; ++k) hsB[k] = __builtin_amdgcn_readlane(hb, 48 + k);
        __builtin_amdgcn_sched_barrier(0);
        // ---- FMA batch 3
        #pragma unroll
        for (int k = 0; k < 16; k += 4) {
            a0 = fmaf(w[48+k+0], __int_as_float(hsB[k+0]), a0);
            a1 = fmaf(w[48+k+1], __int_as_float(hsB[k+1]), a1);
            a2 = fmaf(w[48+k+2], __int_as_float(hsB[k+2]), a2);
            a3 = fmaf(w[48+k+3], __int_as_float(hsB[k+3]), a3);
        }

        // x contribution last (its LDS wait lands here, long since done)
        float acc = ((a0 + a1) + (a2 + a3));
        acc = fmaf(wi0, xv.x, acc);
        acc = fmaf(wi1, xv.y, acc);

        // unified activation: 1 mul + v_exp + add + rcp + fma
        const float act = fmaf(actA, fast_rcp(1.0f + fast_exp2(actB2 * acc)), actC);

        const int buf = t & 1;
        gbuf[buf][gate][lane] = act;        // conflict-free (contiguous per wave)
        fast_barrier();                     // the only per-step barrier (lgkm-only)

        // ---- update phase (redundant in all 4 waves; keeps h,c replicated)
        // ordered i,f,g first (feed cval chain), o last (needed latest)
        const float gi = gbuf[buf][0][lane];
        const float gf = gbuf[buf][1][lane];
        const float gg = gbuf[buf][2][lane];
        cval = fmaf(gf, cval, gi * gg);
        // tanh(c) = 1 - 2*rcp(2^(2*log2e*c)+1)
        const float th = 1.0f - 2.0f * fast_rcp(fast_exp2((2.0f * LOG2E) * cval) + 1.0f);
        const float go = gbuf[buf][3][lane];
        hval = go * th;

        // h history: wave 0 stores directly (coalesced 256B; vmcnt never
        // drained in-loop thanks to the lgkm-only barrier)
        if (gate == 0) hist[t * HID + lane] = hval;
    }

    __syncthreads();  // full drain: wave0's hist stores retired & visible

    // ---- projection: out[t,o] = b_fc[o] + dot(W_fc[o,:], hist[t,:])
    #pragma unroll
    for (int j = 0; j < 8; ++j) {
        const int idx = tid + j * 256;      // 0..2047, coalesced stores
        const int t   = idx >> 1;
        const int o   = idx & 1;
        const float4* hv4 = (const float4*)(hist + t * HID);
        const float4* wv  = (const float4*)(W_fc + o * HID);
        float p0 = 0.f, p1 = 0.f, p2 = 0.f, p3 = 0.f;
        #pragma unroll
        for (int k = 0; k < HID / 4; ++k) {
            float4 h4 = hv4[k], w4 = wv[k];
            p0 = fmaf(h4.x, w4.x, p0);
            p1 = fmaf(h4.y, w4.y, p1);
            p2 = fmaf(h4.z, w4.z, p2);
            p3 = fmaf(h4.w, w4.w, p3);
        }
        out[idx] = b_fc[o] + ((p0 + p1) + (p2 + p3));
    }
}

extern "C" void kernel_launch(void* const* d_in, const int* in_sizes, int n_in,
                              void* d_out, int out_size, void* d_ws, size_t ws_size,
                              hipStream_t stream) {
    const float* x    = (const float*)d_in[0];
    const float* W_ih = (const float*)d_in[1];
    const float* W_hh = (const float*)d_in[2];
    const float* b_ih = (const float*)d_in[3];
    const float* b_hh = (const float*)d_in[4];
    const float* W_fc = (const float*)d_in[5];
    const float* b_fc = (const float*)d_in[6];
    float* out  = (float*)d_out;
    float* hist = (float*)d_ws;   // needs 1024*64*4 = 256 KB

    lstm_seq_kernel<<<dim3(1), dim3(256), 0, stream>>>(
        x, W_ih, W_hh, b_ih, b_hh, W_fc, b_fc, out, hist);
}